// Round 3
// baseline (3377.019 us; speedup 1.0000x reference)
//
#include <hip/hip_runtime.h>

namespace {

constexpr int Hn = 50;    // hidden size
constexpr int Bn = 2048;  // batch
constexpr int Tn = 512;   // sequence length

__device__ __forceinline__ float fsig(float x) {
  return 1.0f / (1.0f + __expf(-x));  // x<<0 -> exp=inf -> 0 : safe
}
__device__ __forceinline__ float ftanh(float x) {
  float a = fabsf(x);
  float e = __expf(-2.0f * a);        // in (0,1]
  float t = (1.0f - e) / (1.0f + e);
  return copysignf(t, x);
}
__device__ __forceinline__ float rlane(float v, int k) {
  return __builtin_bit_cast(float, __builtin_amdgcn_readlane(__builtin_bit_cast(int, v), k));
}

// ============================================================================
// Gate-per-wave LSTM. Block = 256 threads = 4 waves = 4 batch elements.
// Wave wv owns gate wv (0:i 1:f 2:g 3:o): holds the concatenated weight row
// [Wih | Whh] for cell q = lane (104 floats, static VGPR array - no spill).
// u = [x_t ; h_{t-1}] per element lives in LDS; reads are wave-uniform
// (same-address broadcast ds_read_b128, conflict-free). Gates exchanged via
// s_g; wave wv performs the full cell update for element wv. fp32 throughout.
// ============================================================================

// -------- Layers 2/3: input sequence [T][B][H] --------
template <bool WRITE_H, bool DO_FC>
__global__ __launch_bounds__(256, 2) void lstm_mid(
    const float* __restrict__ xseq,  // [T][B][H] (may alias hseq: in-place ok)
    const float* __restrict__ wih,   // [4H][H]
    const float* __restrict__ whh,   // [4H][H]
    const float* __restrict__ bias,  // [4H]
    float* __restrict__ hseq,        // [T][B][H]
    const float* __restrict__ wfc,   // [H]
    const float* __restrict__ bfc,   // [1]
    float* __restrict__ out)         // [B]
{
  __shared__ float s_u[4][112];      // [elem][k]: 0..49 x, 50..99 h, 100..103 pad
  __shared__ float s_g[4][4][52];    // [elem][gate][cell]

  const int lane = threadIdx.x & 63;
  const int wv   = threadIdx.x >> 6;   // gate index
  const int eb   = blockIdx.x * 4;
  const int me   = eb + wv;            // element this wave cell-updates
  const bool act = lane < Hn;
  const int q    = act ? lane : 0;
  const int wrow = wv * Hn + q;

  float wk[104];
#pragma unroll
  for (int k = 0; k < Hn; ++k) wk[k] = wih[wrow * Hn + k];
#pragma unroll
  for (int k = 0; k < Hn; ++k) wk[Hn + k] = whh[wrow * Hn + k];
  wk[100] = wk[101] = wk[102] = wk[103] = 0.f;
  const float bb = act ? bias[wrow] : 0.f;

  for (int i = threadIdx.x; i < 4 * 112; i += 256) ((float*)s_u)[i] = 0.f;
  __syncthreads();
  if (act) s_u[wv][lane] = xseq[(size_t)me * Hn + lane];  // x_0
  __syncthreads();

  float c = 0.f, h = 0.f;

#pragma unroll 1
  for (int t = 0; t < Tn; ++t) {
    const int tn = (t + 1 < Tn) ? t + 1 : t;
    const float xnext = act ? xseq[((size_t)tn * Bn + me) * Hn + lane] : 0.f;

    float a0 = bb, a1 = bb, a2 = bb, a3 = bb;
#pragma unroll
    for (int kb = 0; kb < 26; ++kb) {
      const float4 u0 = *(const float4*)&s_u[0][kb * 4];
      const float4 u1 = *(const float4*)&s_u[1][kb * 4];
      const float4 u2 = *(const float4*)&s_u[2][kb * 4];
      const float4 u3 = *(const float4*)&s_u[3][kb * 4];
      const float w0 = wk[kb * 4 + 0], w1 = wk[kb * 4 + 1];
      const float w2 = wk[kb * 4 + 2], w3 = wk[kb * 4 + 3];
      a0 = fmaf(w0, u0.x, a0); a0 = fmaf(w1, u0.y, a0);
      a0 = fmaf(w2, u0.z, a0); a0 = fmaf(w3, u0.w, a0);
      a1 = fmaf(w0, u1.x, a1); a1 = fmaf(w1, u1.y, a1);
      a1 = fmaf(w2, u1.z, a1); a1 = fmaf(w3, u1.w, a1);
      a2 = fmaf(w0, u2.x, a2); a2 = fmaf(w1, u2.y, a2);
      a2 = fmaf(w2, u2.z, a2); a2 = fmaf(w3, u2.w, a2);
      a3 = fmaf(w0, u3.x, a3); a3 = fmaf(w1, u3.y, a3);
      a3 = fmaf(w2, u3.z, a3); a3 = fmaf(w3, u3.w, a3);
    }
    if (act) {
      s_g[0][wv][q] = a0;
      s_g[1][wv][q] = a1;
      s_g[2][wv][q] = a2;
      s_g[3][wv][q] = a3;
    }
    __syncthreads();

    const float gi = s_g[wv][0][q], gf = s_g[wv][1][q];
    const float gg = s_g[wv][2][q], go = s_g[wv][3][q];
    const float I = fsig(gi), F = fsig(gf), G = ftanh(gg), O = fsig(go);
    c = fmaf(F, c, I * G);
    h = O * ftanh(c);

    if (act) {
      s_u[wv][Hn + lane] = h;
      s_u[wv][lane] = xnext;
      if (WRITE_H) hseq[((size_t)t * Bn + me) * Hn + lane] = h;
    }
    __syncthreads();
  }

  if (DO_FC) {
    float p = act ? h * wfc[q] : 0.f;
#pragma unroll
    for (int off = 32; off > 0; off >>= 1) p += __shfl_xor(p, off);
    if (lane == 0) out[me] = p + bfc[0];
  }
}

// -------- Layer 1: scalar input x[B][T] --------
__global__ __launch_bounds__(256, 2) void lstm_first(
    const float* __restrict__ x,     // [B][T]
    const float* __restrict__ wih,   // [4H][1]
    const float* __restrict__ whh,   // [4H][H]
    const float* __restrict__ bias,  // [4H]
    float* __restrict__ hseq)        // [T][B][H]
{
  __shared__ float s_h[4][52];       // [elem][cell] (50,51 pad = 0)
  __shared__ float s_g[4][4][52];

  const int lane = threadIdx.x & 63;
  const int wv   = threadIdx.x >> 6;
  const int eb   = blockIdx.x * 4;
  const int me   = eb + wv;
  const bool act = lane < Hn;
  const int q    = act ? lane : 0;
  const int wrow = wv * Hn + q;

  float wk[52];
#pragma unroll
  for (int k = 0; k < Hn; ++k) wk[k] = whh[wrow * Hn + k];
  wk[50] = wk[51] = 0.f;
  const float wihs = wih[wrow];
  const float bb = act ? bias[wrow] : 0.f;

  for (int i = threadIdx.x; i < 4 * 52; i += 256) ((float*)s_h)[i] = 0.f;
  __syncthreads();

  float c = 0.f, h = 0.f;

#pragma unroll 1
  for (int tb = 0; tb < Tn; tb += 64) {
    // stage 64 timesteps of x for all 4 elements across lanes
    const float xv0 = x[(size_t)(eb + 0) * Tn + tb + lane];
    const float xv1 = x[(size_t)(eb + 1) * Tn + tb + lane];
    const float xv2 = x[(size_t)(eb + 2) * Tn + tb + lane];
    const float xv3 = x[(size_t)(eb + 3) * Tn + tb + lane];
#pragma unroll 1
    for (int ti = 0; ti < 64; ++ti) {
      float a0 = fmaf(wihs, rlane(xv0, ti), bb);
      float a1 = fmaf(wihs, rlane(xv1, ti), bb);
      float a2 = fmaf(wihs, rlane(xv2, ti), bb);
      float a3 = fmaf(wihs, rlane(xv3, ti), bb);
#pragma unroll
      for (int kb = 0; kb < 13; ++kb) {
        const float4 u0 = *(const float4*)&s_h[0][kb * 4];
        const float4 u1 = *(const float4*)&s_h[1][kb * 4];
        const float4 u2 = *(const float4*)&s_h[2][kb * 4];
        const float4 u3 = *(const float4*)&s_h[3][kb * 4];
        const float w0 = wk[kb * 4 + 0], w1 = wk[kb * 4 + 1];
        const float w2 = wk[kb * 4 + 2], w3 = wk[kb * 4 + 3];
        a0 = fmaf(w0, u0.x, a0); a0 = fmaf(w1, u0.y, a0);
        a0 = fmaf(w2, u0.z, a0); a0 = fmaf(w3, u0.w, a0);
        a1 = fmaf(w0, u1.x, a1); a1 = fmaf(w1, u1.y, a1);
        a1 = fmaf(w2, u1.z, a1); a1 = fmaf(w3, u1.w, a1);
        a2 = fmaf(w0, u2.x, a2); a2 = fmaf(w1, u2.y, a2);
        a2 = fmaf(w2, u2.z, a2); a2 = fmaf(w3, u2.w, a2);
        a3 = fmaf(w0, u3.x, a3); a3 = fmaf(w1, u3.y, a3);
        a3 = fmaf(w2, u3.z, a3); a3 = fmaf(w3, u3.w, a3);
      }
      if (act) {
        s_g[0][wv][q] = a0;
        s_g[1][wv][q] = a1;
        s_g[2][wv][q] = a2;
        s_g[3][wv][q] = a3;
      }
      __syncthreads();

      const float gi = s_g[wv][0][q], gf = s_g[wv][1][q];
      const float gg = s_g[wv][2][q], go = s_g[wv][3][q];
      const float I = fsig(gi), F = fsig(gf), G = ftanh(gg), O = fsig(go);
      c = fmaf(F, c, I * G);
      h = O * ftanh(c);

      if (act) {
        s_h[wv][lane] = h;
        hseq[((size_t)(tb + ti) * Bn + me) * Hn + lane] = h;
      }
      __syncthreads();
    }
  }
}

}  // namespace

extern "C" void kernel_launch(void* const* d_in, const int* in_sizes, int n_in,
                              void* d_out, int out_size, void* d_ws, size_t ws_size,
                              hipStream_t stream) {
  const float* x    = (const float*)d_in[0];
  const float* wih1 = (const float*)d_in[1];
  const float* whh1 = (const float*)d_in[2];
  const float* b1   = (const float*)d_in[3];
  const float* wih2 = (const float*)d_in[4];
  const float* whh2 = (const float*)d_in[5];
  const float* b2   = (const float*)d_in[6];
  const float* wih3 = (const float*)d_in[7];
  const float* whh3 = (const float*)d_in[8];
  const float* b3   = (const float*)d_in[9];
  const float* wfc  = (const float*)d_in[10];
  const float* bfc  = (const float*)d_in[11];
  float* out = (float*)d_out;

  float* buf = (float*)d_ws;  // [T][B][H] fp32 = 200 MiB (fits: verified R1/R2)

  dim3 grid(Bn / 4), blk(256);  // 512 blocks x 4 waves; 4 elems/block
  lstm_first<<<grid, blk, 0, stream>>>(x, wih1, whh1, b1, buf);
  lstm_mid<true, false><<<grid, blk, 0, stream>>>(
      buf, wih2, whh2, b2, buf, nullptr, nullptr, nullptr);
  lstm_mid<false, true><<<grid, blk, 0, stream>>>(
      buf, wih3, whh3, b3, nullptr, wfc, bfc, out);
}